// Round 14
// baseline (3441.810 us; speedup 1.0000x reference)
//
#include <hip/hip_runtime.h>
#include <math.h>

#define NPIX 65536
#define NB   4
#define NK   6
#define TK   8
#define NBUK 48
#define NCH  256
#define GB   128
#define CHSP 2
#define NSEL (NB*NK*TK)
#define CCAP 65536

typedef __attribute__((ext_vector_type(8))) short bf16x8;
typedef __attribute__((ext_vector_type(4))) float f32x4;

#define KEEP(v) asm volatile("" :: "v"(v))

// ---------------- init ----------------
__global__ __launch_bounds__(256) void k_init(unsigned* m_arr, unsigned* Mbits,
                                              unsigned* hist0) {
  int i = blockIdx.x * 256 + threadIdx.x;
  if (i < NB * NK) { m_arr[i] = 0u; Mbits[i] = 0u; }
  for (int j = i; j < NB * NK * 256; j += 256 * 8) hist0[j] = 0u;
}

// ---------------- A1: cert/argmax/m/M + pass-0 hist + ballot compaction ----------------
__global__ __launch_bounds__(256) void k_cert(const float* __restrict__ preds,
    float* __restrict__ cert, unsigned char* __restrict__ argm,
    unsigned* __restrict__ m_arr, unsigned* __restrict__ Mbits,
    unsigned* __restrict__ hist0, float* __restrict__ clist) {
  __shared__ unsigned s_max[NK];
  __shared__ unsigned s_hist[NK * 256];
  __shared__ unsigned s_seg[4][4][NK];
  __shared__ unsigned s_segbase[4][4][NK];
  __shared__ unsigned s_bbase[NK];
  int tid = threadIdx.x;
  int w = tid >> 6, lane = tid & 63;
  if (tid < NK) s_max[tid] = 0u;
  for (int j = tid; j < NK * 256; j += 256) s_hist[j] = 0u;
  __syncthreads();
  int i = blockIdx.x * 256 + tid;
  int n4 = i << 2;
  int b = n4 >> 16;
  int n = n4 & (NPIX - 1);
  const float* pb = preds + (size_t)b * NK * NPIX + n;
  float4 pv[NK];
  #pragma unroll
  for (int k = 0; k < NK; ++k) pv[k] = *(const float4*)(pb + (size_t)k * NPIX);
  float cv[4]; int cls[4]; unsigned av = 0;
  #pragma unroll
  for (int j = 0; j < 4; ++j) {
    float m1 = -INFINITY, m2 = -INFINITY; int arg = 0;
    #pragma unroll
    for (int k = 0; k < NK; ++k) {
      float v = (j == 0) ? pv[k].x : (j == 1) ? pv[k].y : (j == 2) ? pv[k].z : pv[k].w;
      if (v > m1) { m2 = m1; m1 = v; arg = k; }
      else if (v > m2) m2 = v;
    }
    cv[j] = m1 - m2;
    cls[j] = arg;
    av |= ((unsigned)arg) << (8 * j);
    unsigned u = __float_as_uint(cv[j]);
    atomicMax(&s_max[arg], u);
    atomicAdd(&s_hist[arg * 256 + (u >> 24)], 1u);
  }
  *(float4*)(cert + (size_t)b * NPIX + n) = make_float4(cv[0], cv[1], cv[2], cv[3]);
  *(unsigned*)(argm + (size_t)b * NPIX + n) = av;
  unsigned long long lmask = ((unsigned long long)1 << lane) - 1ull;
  unsigned myoff[4];
  #pragma unroll
  for (int j = 0; j < 4; ++j) {
    #pragma unroll
    for (int c = 0; c < NK; ++c) {
      unsigned long long mk = __ballot(cls[j] == c);
      if (cls[j] == c) myoff[j] = (unsigned)__popcll(mk & lmask);
      if (lane == 0) s_seg[w][j][c] = (unsigned)__popcll(mk);
    }
  }
  __syncthreads();
  if (tid < NK) {
    unsigned run = 0;
    #pragma unroll
    for (int s = 0; s < 16; ++s) {
      unsigned v = s_seg[s >> 2][s & 3][tid];
      s_segbase[s >> 2][s & 3][tid] = run;
      run += v;
    }
    s_bbase[tid] = atomicAdd(&m_arr[b * NK + tid], run);
    atomicMax(&Mbits[b * NK + tid], s_max[tid]);
  }
  __syncthreads();
  for (int j = tid; j < NK * 256; j += 256)
    if (s_hist[j]) atomicAdd(&hist0[b * NK * 256 + j], s_hist[j]);
  #pragma unroll
  for (int j = 0; j < 4; ++j) {
    int c = cls[j];
    clist[(size_t)(b * NK + c) * CCAP + s_bbase[c] + s_segbase[w][j][c] + myoff[j]] = cv[j];
  }
}

// ---------------- A2 ----------------
__global__ __launch_bounds__(256) void k_thresh(const float* __restrict__ clist,
    const unsigned* __restrict__ hist0, const unsigned* __restrict__ m_arr,
    float* __restrict__ thr) {
  int g = blockIdx.x;
  int bc = g >> 3;
  int t = g & 7;
  int tid = threadIdx.x;
  __shared__ unsigned hist[256];
  __shared__ unsigned s_sel, s_rank;
  unsigned m = m_arr[bc];
  if (m == 0) { if (tid == 0) thr[g] = 0.f; return; }
  unsigned long long ks = ((unsigned long long)m * (unsigned)(t + 1)) / TK;
  unsigned rank = ks ? (unsigned)ks : 1u;
  unsigned prefix = 0;
  {
    const unsigned* h = hist0 + bc * 256;
    unsigned cum = 0;
    for (int bin = 255; bin >= 0; --bin) {
      unsigned hh = h[bin]; cum += hh;
      if (cum >= rank) { prefix = (unsigned)bin; rank = rank - (cum - hh); break; }
    }
  }
  const unsigned* lp = (const unsigned*)clist + (size_t)bc * CCAP;
  for (int pass = 1; pass < 4; ++pass) {
    int shift = 24 - 8 * pass;
    hist[tid] = 0u;
    __syncthreads();
    for (unsigned idx = tid; idx < m; idx += 256) {
      unsigned u = lp[idx];
      if ((u >> (shift + 8)) == prefix)
        atomicAdd(&hist[(u >> shift) & 255u], 1u);
    }
    __syncthreads();
    if (tid == 0) {
      unsigned cum = 0, rn = rank, sel = 0;
      for (int bin = 255; bin >= 0; --bin) {
        unsigned hh = hist[bin]; cum += hh;
        if (cum >= rank) { sel = (unsigned)bin; rn = rank - (cum - hh); break; }
      }
      s_sel = sel; s_rank = rn;
    }
    __syncthreads();
    prefix = (prefix << 8) | s_sel;
    rank = s_rank;
    __syncthreads();
  }
  if (tid == 0) thr[g] = __uint_as_float(prefix);
}

// ---------------- A3 ----------------
__global__ __launch_bounds__(256) void k_bucket(const float* __restrict__ cert,
    const unsigned char* __restrict__ argm, const unsigned* __restrict__ Mbits,
    const float* __restrict__ thr, unsigned* __restrict__ eb_out,
    float* __restrict__ zpart) {
  __shared__ float zacc[4 * NBUK * 64];
  __shared__ float wpart[4 * NBUK];
  __shared__ float s_thr[NSEL];
  __shared__ float s_M[NB * NK];
  int tid = threadIdx.x;
  int w = tid >> 6, lane = tid & 63;
  float* mycol = zacc + (size_t)w * NBUK * 64 + lane;
  if (tid < NSEL) s_thr[tid] = thr[tid];
  if (tid < NB * NK) s_M[tid] = __uint_as_float(Mbits[tid]);
  #pragma unroll
  for (int k = 0; k < NBUK; ++k) mycol[k * 64] = 0.f;
  __syncthreads();
  int i = blockIdx.x * 256 + tid;
  int n4 = i << 2;
  int b = n4 >> 16;
  int n = n4 & (NPIX - 1);
  float4 cv = *(const float4*)(cert + (size_t)b * NPIX + n);
  unsigned av = *(const unsigned*)(argm + (size_t)b * NPIX + n);
  unsigned evv[4];
  #pragma unroll
  for (int j = 0; j < 4; ++j) {
    int c = (av >> (8 * j)) & 255;
    float ce = (j == 0) ? cv.x : (j == 1) ? cv.y : (j == 2) ? cv.z : cv.w;
    float e = expf(ce - s_M[b * NK + c]);
    const float* tc = &s_thr[(b * NK + c) * TK];
    int tmin = TK - 1;
    #pragma unroll
    for (int tt = TK - 2; tt >= 0; --tt) if (ce >= tc[tt]) tmin = tt;
    evv[j] = (__float_as_uint(e) & 0xFFFFFFC0u) | (unsigned)(c * TK + tmin);
    mycol[(evv[j] & 63u) * 64] += __uint_as_float(evv[j] & 0xFFFF0000u);
  }
  uint4 ev; ev.x = evv[0]; ev.y = evv[1]; ev.z = evv[2]; ev.w = evv[3];
  *(uint4*)(eb_out + (size_t)b * NPIX + n) = ev;
  __syncthreads();
  for (int k = 0; k < NBUK; ++k) {
    float v = mycol[k * 64];
    #pragma unroll
    for (int d = 1; d < 64; d <<= 1) v += __shfl_xor(v, d, 64);
    if (lane == 0) wpart[w * NBUK + k] = v;
  }
  __syncthreads();
  if (tid < NBUK)
    zpart[(size_t)blockIdx.x * NBUK + tid] =
      wpart[tid] + wpart[NBUK + tid] + wpart[2 * NBUK + tid] + wpart[3 * NBUK + tid];
}

// ---------------- Zred ----------------
__global__ __launch_bounds__(192) void k_zred(const float* __restrict__ zpart,
                                              float* __restrict__ zfin) {
  int t = threadIdx.x;
  int b = t / NBUK, k = t % NBUK;
  float s = 0.f;
  for (int i = 0; i < 64; ++i) s += zpart[(size_t)(b * 64 + i) * NBUK + k];
  zfin[b * NBUK + k] = s;
}

// ---------------- B: MFMA GEMM (R11 version, measured 51.3 us) ----------
__global__ __launch_bounds__(512) void k_gemm(const float* __restrict__ x,
    const unsigned* __restrict__ eb, float* __restrict__ psum) {
  __shared__ char smem[49152];
  short* E = (short*)smem;
  int tid = threadIdx.x;
  int w = tid >> 6, lane = tid & 63;
  int bid = blockIdx.x;
  int g = bid & (GB - 1);
  int chh = (bid >> 7) & (CHSP - 1);
  int b = bid >> 8;
  const unsigned* ebp = eb + (size_t)b * NPIX + g * 512;
  const float* xb = x + ((size_t)b * NCH + chh * 128) * NPIX;
  int chl = w * 16 + (lane & 15);
  f32x4 acc[3];
  #pragma unroll
  for (int m = 0; m < 3; ++m) acc[m] = (f32x4){0.f, 0.f, 0.f, 0.f};
  #pragma unroll
  for (int z = 0; z < 6; ++z)
    ((uint4*)E)[z * 512 + tid] = (uint4){0u, 0u, 0u, 0u};
  __syncthreads();
  {
    unsigned u = ebp[tid];
    unsigned bk = u & 63u;
    int ks = tid >> 5, k = tid & 31;
    int el = (int)(bk & 15u) + ((k >> 3) << 4);
    E[((ks * 3 + (int)(bk >> 4)) * 64 + el) * 8 + (k & 7)] = (short)(u >> 16);
  }
  __syncthreads();
  const float* xrow = xb + (size_t)chl * NPIX + g * 512 + ((lane >> 4) << 3);
  float4 xa[4], xc[4];
  #pragma unroll
  for (int p = 0; p < 3; ++p) {
    xa[p] = *(const float4*)(xrow + p * 32);
    xc[p] = *(const float4*)(xrow + p * 32 + 4);
  }
  #pragma unroll
  for (int ks = 0; ks < 16; ++ks) {
    if (ks + 3 < 16) {
      xa[(ks + 3) & 3] = *(const float4*)(xrow + (ks + 3) * 32);
      xc[(ks + 3) & 3] = *(const float4*)(xrow + (ks + 3) * 32 + 4);
    }
    bf16x8 A0 = ((bf16x8*)E)[(ks * 3 + 0) * 64 + lane];
    bf16x8 A1 = ((bf16x8*)E)[(ks * 3 + 1) * 64 + lane];
    bf16x8 A2 = ((bf16x8*)E)[(ks * 3 + 2) * 64 + lane];
    float4 va = xa[ks & 3], vc = xc[ks & 3];
    float xv[8] = {va.x, va.y, va.z, va.w, vc.x, vc.y, vc.z, vc.w};
    bf16x8 Bh, Bl;
    #pragma unroll
    for (int j = 0; j < 8; ++j) {
      unsigned u = __float_as_uint(xv[j]);
      float hf = __uint_as_float(u & 0xFFFF0000u);
      float lo = xv[j] - hf;
      Bh[j] = (short)(u >> 16);
      Bl[j] = (short)(__float_as_uint(lo) >> 16);
    }
    acc[0] = __builtin_amdgcn_mfma_f32_16x16x32_bf16(A0, Bh, acc[0], 0, 0, 0);
    acc[1] = __builtin_amdgcn_mfma_f32_16x16x32_bf16(A1, Bh, acc[1], 0, 0, 0);
    acc[2] = __builtin_amdgcn_mfma_f32_16x16x32_bf16(A2, Bh, acc[2], 0, 0, 0);
    acc[0] = __builtin_amdgcn_mfma_f32_16x16x32_bf16(A0, Bl, acc[0], 0, 0, 0);
    acc[1] = __builtin_amdgcn_mfma_f32_16x16x32_bf16(A1, Bl, acc[1], 0, 0, 0);
    acc[2] = __builtin_amdgcn_mfma_f32_16x16x32_bf16(A2, Bl, acc[2], 0, 0, 0);
  }
  __syncthreads();
  float* Ct = (float*)smem;
  #pragma unroll
  for (int m = 0; m < 3; ++m)
    #pragma unroll
    for (int i = 0; i < 4; ++i)
      Ct[chl * 52 + m * 16 + ((lane >> 4) << 2) + i] = acc[m][i];
  __syncthreads();
  float* dst = psum + ((size_t)g * NB * NCH + (size_t)b * NCH + chh * 128) * NBUK;
  int r = tid >> 2, p = tid & 3;
  #pragma unroll
  for (int j = 0; j < 3; ++j) {
    float4 v = *(const float4*)(Ct + r * 52 + p * 12 + j * 4);
    *(float4*)(dst + r * NBUK + p * 12 + j * 4) = v;
  }
}

// ---------------- F ----------------
__global__ __launch_bounds__(64) void k_final(const float* __restrict__ psum,
    const float* __restrict__ zfin, const unsigned* __restrict__ m_arr,
    float* __restrict__ out) {
  int bc_ = blockIdx.x;
  int lane = threadIdx.x;
  int b = bc_ >> 8;
  float p48[NBUK];
  #pragma unroll
  for (int k = 0; k < NBUK; ++k) p48[k] = 0.f;
  #pragma unroll
  for (int gg = 0; gg < GB / 64; ++gg) {
    const float* ps = psum + ((size_t)(gg * 64 + lane) * NB * NCH + bc_) * NBUK;
    #pragma unroll
    for (int i = 0; i < 12; ++i) {
      float4 v = ((const float4*)ps)[i];
      p48[4 * i] += v.x; p48[4 * i + 1] += v.y; p48[4 * i + 2] += v.z; p48[4 * i + 3] += v.w;
    }
  }
  #pragma unroll
  for (int d = 1; d < 64; d <<= 1)
    #pragma unroll
    for (int k = 0; k < NBUK; ++k) p48[k] += __shfl_xor(p48[k], d, 64);
  if (lane == 0) {
    float* fs = out + (size_t)bc_ * NBUK;
    float* fg = out + (size_t)NB * NCH * NBUK + (size_t)bc_ * NK;
    float t5[TK];
    #pragma unroll
    for (int c = 0; c < NK; ++c) {
      unsigned m = m_arr[b * NK + c];
      float P = 0.f, Z = 0.f;
      float vals[TK];
      #pragma unroll
      for (int t = 0; t < TK; ++t) {
        P += p48[c * TK + t];
        Z += zfin[b * NBUK + c * TK + t];
        vals[t] = P / Z;
      }
      float tot = vals[TK - 1];
      #pragma unroll
      for (int t = 0; t < TK; ++t) {
        float v = (m == 0u) ? 0.f : ((m < (unsigned)TK) ? tot : vals[t]);
        fs[c * TK + t] = v;
        if (c == NK - 1) t5[t] = v;
      }
    }
    #pragma unroll
    for (int v = 0; v < NK; ++v) fg[v] = t5[2 + v];
  }
}

// ================= PROBES (read-only, rep-looped, keep-alive) =================

__global__ __launch_bounds__(256) void p_cert(const float* __restrict__ preds) {
  __shared__ unsigned s_max[NK];
  __shared__ unsigned s_hist[NK * 256];
  __shared__ unsigned s_seg[4][4][NK];
  __shared__ unsigned s_segbase[4][4][NK];
  int tid = threadIdx.x;
  int w = tid >> 6, lane = tid & 63;
  int i = blockIdx.x * 256 + tid;
  int b = (i << 2) >> 16;
  int n0 = (i << 2) & (NPIX - 1);
  for (int rep = 0; rep < 32; ++rep) {
    if (tid < NK) s_max[tid] = 0u;
    for (int j = tid; j < NK * 256; j += 256) s_hist[j] = 0u;
    __syncthreads();
    int n = (n0 + rep * 4096) & (NPIX - 1);    // rotate: defeat load hoisting, stay cached
    const float* pb = preds + (size_t)b * NK * NPIX + n;
    float4 pv[NK];
    #pragma unroll
    for (int k = 0; k < NK; ++k) pv[k] = *(const float4*)(pb + (size_t)k * NPIX);
    float cv[4]; int cls[4]; unsigned av = 0;
    #pragma unroll
    for (int j = 0; j < 4; ++j) {
      float m1 = -INFINITY, m2 = -INFINITY; int arg = 0;
      #pragma unroll
      for (int k = 0; k < NK; ++k) {
        float v = (j == 0) ? pv[k].x : (j == 1) ? pv[k].y : (j == 2) ? pv[k].z : pv[k].w;
        if (v > m1) { m2 = m1; m1 = v; arg = k; }
        else if (v > m2) m2 = v;
      }
      cv[j] = m1 - m2; cls[j] = arg;
      av |= ((unsigned)arg) << (8 * j);
      unsigned u = __float_as_uint(cv[j]);
      atomicMax(&s_max[arg], u);
      atomicAdd(&s_hist[arg * 256 + (u >> 24)], 1u);
    }
    KEEP(cv[0]); KEEP(cv[1]); KEEP(cv[2]); KEEP(cv[3]); KEEP(av);
    unsigned long long lmask = ((unsigned long long)1 << lane) - 1ull;
    unsigned myoff[4];
    #pragma unroll
    for (int j = 0; j < 4; ++j) {
      #pragma unroll
      for (int c = 0; c < NK; ++c) {
        unsigned long long mk = __ballot(cls[j] == c);
        if (cls[j] == c) myoff[j] = (unsigned)__popcll(mk & lmask);
        if (lane == 0) s_seg[w][j][c] = (unsigned)__popcll(mk);
      }
    }
    __syncthreads();
    if (tid < NK) {
      unsigned run = 0;
      #pragma unroll
      for (int s = 0; s < 16; ++s) {
        unsigned v = s_seg[s >> 2][s & 3][tid];
        s_segbase[s >> 2][s & 3][tid] = run;
        run += v;
      }
      KEEP(run); KEEP(s_max[tid]);
    }
    __syncthreads();
    for (int j = tid; j < NK * 256; j += 256) { unsigned hv = s_hist[j]; KEEP(hv); }
    #pragma unroll
    for (int j = 0; j < 4; ++j) {
      unsigned addr = s_segbase[w][j][cls[j]] + myoff[j];
      KEEP(addr); KEEP(cv[j]);
    }
    __syncthreads();
  }
}

__global__ __launch_bounds__(256) void p_thresh(const float* __restrict__ clist,
    const unsigned* __restrict__ hist0, const unsigned* __restrict__ m_arr) {
  int g = blockIdx.x;
  int bc = g >> 3;
  int t = g & 7;
  int tid = threadIdx.x;
  __shared__ unsigned hist[256];
  __shared__ unsigned s_sel, s_rank;
  unsigned m = m_arr[bc];
  if (m == 0) return;
  const unsigned* lp = (const unsigned*)clist + (size_t)bc * CCAP;
  for (int rep = 0; rep < 32; ++rep) {
    unsigned long long ks = ((unsigned long long)m * (unsigned)(t + 1)) / TK;
    unsigned rank = ks ? (unsigned)ks : 1u;
    unsigned prefix = 0;
    {
      const unsigned* h = hist0 + bc * 256;
      unsigned cum = 0;
      for (int bin = 255; bin >= 0; --bin) {
        unsigned hh = h[bin]; cum += hh;
        if (cum >= rank) { prefix = (unsigned)bin; rank = rank - (cum - hh); break; }
      }
    }
    for (int pass = 1; pass < 4; ++pass) {
      int shift = 24 - 8 * pass;
      hist[tid] = 0u;
      __syncthreads();
      for (unsigned idx = tid; idx < m; idx += 256) {
        unsigned u = lp[idx];
        if ((u >> (shift + 8)) == prefix)
          atomicAdd(&hist[(u >> shift) & 255u], 1u);
      }
      __syncthreads();
      if (tid == 0) {
        unsigned cum = 0, rn = rank, sel = 0;
        for (int bin = 255; bin >= 0; --bin) {
          unsigned hh = hist[bin]; cum += hh;
          if (cum >= rank) { sel = (unsigned)bin; rn = rank - (cum - hh); break; }
        }
        s_sel = sel; s_rank = rn;
      }
      __syncthreads();
      prefix = (prefix << 8) | s_sel;
      rank = s_rank;
      __syncthreads();
    }
    KEEP(prefix); KEEP(rank);
  }
}

__global__ __launch_bounds__(256) void p_bucket(const float* __restrict__ cert,
    const unsigned char* __restrict__ argm, const unsigned* __restrict__ Mbits,
    const float* __restrict__ thr) {
  __shared__ float zacc[4 * NBUK * 64];
  __shared__ float wpart[4 * NBUK];
  __shared__ float s_thr[NSEL];
  __shared__ float s_M[NB * NK];
  int tid = threadIdx.x;
  int w = tid >> 6, lane = tid & 63;
  float* mycol = zacc + (size_t)w * NBUK * 64 + lane;
  if (tid < NSEL) s_thr[tid] = thr[tid];
  if (tid < NB * NK) s_M[tid] = __uint_as_float(Mbits[tid]);
  int i = blockIdx.x * 256 + tid;
  int b = (i << 2) >> 16;
  int n0 = (i << 2) & (NPIX - 1);
  for (int rep = 0; rep < 48; ++rep) {
    #pragma unroll
    for (int k = 0; k < NBUK; ++k) mycol[k * 64] = 0.f;
    __syncthreads();
    int n = (n0 + rep * 4096) & (NPIX - 1);
    float4 cv = *(const float4*)(cert + (size_t)b * NPIX + n);
    unsigned av = *(const unsigned*)(argm + (size_t)b * NPIX + n);
    unsigned evv[4];
    #pragma unroll
    for (int j = 0; j < 4; ++j) {
      int c = (av >> (8 * j)) & 255;
      float ce = (j == 0) ? cv.x : (j == 1) ? cv.y : (j == 2) ? cv.z : cv.w;
      float e = expf(ce - s_M[b * NK + c]);
      const float* tc = &s_thr[(b * NK + c) * TK];
      int tmin = TK - 1;
      #pragma unroll
      for (int tt = TK - 2; tt >= 0; --tt) if (ce >= tc[tt]) tmin = tt;
      evv[j] = (__float_as_uint(e) & 0xFFFFFFC0u) | (unsigned)(c * TK + tmin);
      mycol[(evv[j] & 63u) * 64] += __uint_as_float(evv[j] & 0xFFFF0000u);
    }
    KEEP(evv[0]); KEEP(evv[1]); KEEP(evv[2]); KEEP(evv[3]);
    __syncthreads();
    for (int k = 0; k < NBUK; ++k) {
      float v = mycol[k * 64];
      #pragma unroll
      for (int d = 1; d < 64; d <<= 1) v += __shfl_xor(v, d, 64);
      if (lane == 0) wpart[w * NBUK + k] = v;
    }
    __syncthreads();
    if (tid < NBUK) {
      float s = wpart[tid] + wpart[NBUK + tid] + wpart[2 * NBUK + tid] + wpart[3 * NBUK + tid];
      KEEP(s);
    }
    __syncthreads();
  }
}

__global__ __launch_bounds__(192) void p_zred(const float* __restrict__ zpart) {
  int t = threadIdx.x;
  int b = t / NBUK, k = t % NBUK;
  for (int rep = 0; rep < 128; ++rep) {
    float s = 0.f;
    for (int i = 0; i < 64; ++i)
      s += zpart[(size_t)(b * 64 + ((i + rep) & 63)) * NBUK + k];
    KEEP(s);
  }
}

__global__ __launch_bounds__(64) void p_final(const float* __restrict__ psum,
    const float* __restrict__ zfin, const unsigned* __restrict__ m_arr) {
  int bc_ = blockIdx.x;
  int lane = threadIdx.x;
  int b = bc_ >> 8;
  for (int rep = 0; rep < 32; ++rep) {
    float p48[NBUK];
    #pragma unroll
    for (int k = 0; k < NBUK; ++k) p48[k] = 0.f;
    #pragma unroll
    for (int gg = 0; gg < GB / 64; ++gg) {
      int gi = (gg * 64 + lane + rep) & (GB - 1);
      const float* ps = psum + ((size_t)gi * NB * NCH + bc_) * NBUK;
      #pragma unroll
      for (int i = 0; i < 12; ++i) {
        float4 v = ((const float4*)ps)[i];
        p48[4 * i] += v.x; p48[4 * i + 1] += v.y; p48[4 * i + 2] += v.z; p48[4 * i + 3] += v.w;
      }
    }
    #pragma unroll
    for (int d = 1; d < 64; d <<= 1)
      #pragma unroll
      for (int k = 0; k < NBUK; ++k) p48[k] += __shfl_xor(p48[k], d, 64);
    if (lane == 0) {
      #pragma unroll
      for (int c = 0; c < NK; ++c) {
        unsigned m = m_arr[b * NK + c];
        float P = 0.f, Z = 0.f, last = 0.f;
        #pragma unroll
        for (int t = 0; t < TK; ++t) {
          P += p48[c * TK + t];
          Z += zfin[b * NBUK + c * TK + t];
          last = P / Z;
          KEEP(last);
        }
        KEEP(m); KEEP(last);
      }
    }
  }
}

extern "C" void kernel_launch(void* const* d_in, const int* in_sizes, int n_in,
                              void* d_out, int out_size, void* d_ws, size_t ws_size,
                              hipStream_t stream) {
  const float* x     = (const float*)d_in[0];
  const float* preds = (const float*)d_in[1];
  float* out = (float*)d_out;
  char* ws = (char*)d_ws;
  float*         cert  = (float*)(ws);
  unsigned char* argm  = (unsigned char*)(ws + 0x100000);
  unsigned*      eb    = (unsigned*)(ws + 0x140000);
  float*         clist = (float*)(ws + 0x240000);
  float*         psum  = (float*)(ws + 0x240000);   // union: clist dead after k_thresh
  unsigned*      m_arr = (unsigned*)(ws + 0x1A80000);
  unsigned*      Mbits = (unsigned*)(ws + 0x1A80100);
  float*         thr   = (float*)(ws + 0x1A80200);
  float*         zpart = (float*)(ws + 0x1A81000);
  float*         zfin  = (float*)(ws + 0x1A8E000);
  unsigned*      hist0 = (unsigned*)(ws + 0x1A90000);

  // ---- real chain (R11 exact) ----
  k_init  <<<8, 256, 0, stream>>>(m_arr, Mbits, hist0);
  k_cert  <<<256, 256, 0, stream>>>(preds, cert, argm, m_arr, Mbits, hist0, clist);
  k_thresh<<<NSEL, 256, 0, stream>>>(clist, hist0, m_arr, thr);
  k_bucket<<<256, 256, 0, stream>>>(cert, argm, Mbits, thr, eb, zpart);
  k_zred  <<<1, 192, 0, stream>>>(zpart, zfin);
  k_gemm  <<<NB * CHSP * GB, 512, 0, stream>>>(x, eb, psum);
  k_final <<<NB * NCH, 64, 0, stream>>>(psum, zfin, m_arr, out);
  // ---- probes: read-only, no state mutation; T_kernel = dur/rep ----
  // NOTE: p_thresh/p_bucket read clist/cert regions — psum overwrote clist, so
  // p_thresh uses clist BEFORE overwrite? No: clist and psum share memory and
  // k_gemm already wrote psum. p_thresh reads that region — values differ from
  // the real pass but access pattern/volume identical (it is a timing probe;
  // prefix matching may select different counts — fidelity approximate).
  p_cert  <<<256, 256, 0, stream>>>(preds);
  p_thresh<<<NSEL, 256, 0, stream>>>(clist, hist0, m_arr);
  p_bucket<<<256, 256, 0, stream>>>(cert, argm, Mbits, thr);
  p_zred  <<<1, 192, 0, stream>>>(zpart);
  p_final <<<NB * NCH, 64, 0, stream>>>(psum, zfin, m_arr);
}

// Round 15
// 117.706 us; speedup vs baseline: 29.2406x; 29.2406x over previous
//
#include <hip/hip_runtime.h>
#include <math.h>

#define NPIX 65536
#define NB   4
#define NK   6
#define TK   8
#define NBUK 48
#define NCH  256
#define GB   128
#define CHSP 2
#define NSEL (NB*NK*TK)
#define CCAP 65536

typedef __attribute__((ext_vector_type(8))) short bf16x8;
typedef __attribute__((ext_vector_type(4))) float f32x4;

// ---------------- init: zero atomic targets + pass-0 histograms ----------------
__global__ __launch_bounds__(256) void k_init(unsigned* m_arr, unsigned* Mbits,
                                              unsigned* hist0) {
  int i = blockIdx.x * 256 + threadIdx.x;
  if (i < NB * NK) { m_arr[i] = 0u; Mbits[i] = 0u; }
  for (int j = i; j < NB * NK * 256; j += 256 * 8) hist0[j] = 0u;
}

// ---------------- A1: cert/argmax/m/M + pass-0 hist + ballot compaction ----------------
__global__ __launch_bounds__(256) void k_cert(const float* __restrict__ preds,
    float* __restrict__ cert, unsigned char* __restrict__ argm,
    unsigned* __restrict__ m_arr, unsigned* __restrict__ Mbits,
    unsigned* __restrict__ hist0, float* __restrict__ clist) {
  __shared__ unsigned s_max[NK];
  __shared__ unsigned s_hist[NK * 256];
  __shared__ unsigned s_seg[4][4][NK];
  __shared__ unsigned s_segbase[4][4][NK];
  __shared__ unsigned s_bbase[NK];
  int tid = threadIdx.x;
  int w = tid >> 6, lane = tid & 63;
  if (tid < NK) s_max[tid] = 0u;
  for (int j = tid; j < NK * 256; j += 256) s_hist[j] = 0u;
  __syncthreads();
  int i = blockIdx.x * 256 + tid;
  int n4 = i << 2;
  int b = n4 >> 16;
  int n = n4 & (NPIX - 1);
  const float* pb = preds + (size_t)b * NK * NPIX + n;
  float4 pv[NK];
  #pragma unroll
  for (int k = 0; k < NK; ++k) pv[k] = *(const float4*)(pb + (size_t)k * NPIX);
  float cv[4]; int cls[4]; unsigned av = 0;
  #pragma unroll
  for (int j = 0; j < 4; ++j) {
    float m1 = -INFINITY, m2 = -INFINITY; int arg = 0;
    #pragma unroll
    for (int k = 0; k < NK; ++k) {
      float v = (j == 0) ? pv[k].x : (j == 1) ? pv[k].y : (j == 2) ? pv[k].z : pv[k].w;
      if (v > m1) { m2 = m1; m1 = v; arg = k; }
      else if (v > m2) m2 = v;
    }
    cv[j] = m1 - m2;
    cls[j] = arg;
    av |= ((unsigned)arg) << (8 * j);
    unsigned u = __float_as_uint(cv[j]);
    atomicMax(&s_max[arg], u);
    atomicAdd(&s_hist[arg * 256 + (u >> 24)], 1u);
  }
  *(float4*)(cert + (size_t)b * NPIX + n) = make_float4(cv[0], cv[1], cv[2], cv[3]);
  *(unsigned*)(argm + (size_t)b * NPIX + n) = av;
  unsigned long long lmask = ((unsigned long long)1 << lane) - 1ull;
  unsigned myoff[4];
  #pragma unroll
  for (int j = 0; j < 4; ++j) {
    #pragma unroll
    for (int c = 0; c < NK; ++c) {
      unsigned long long mk = __ballot(cls[j] == c);
      if (cls[j] == c) myoff[j] = (unsigned)__popcll(mk & lmask);
      if (lane == 0) s_seg[w][j][c] = (unsigned)__popcll(mk);
    }
  }
  __syncthreads();
  if (tid < NK) {
    unsigned run = 0;
    #pragma unroll
    for (int s = 0; s < 16; ++s) {
      unsigned v = s_seg[s >> 2][s & 3][tid];
      s_segbase[s >> 2][s & 3][tid] = run;
      run += v;
    }
    s_bbase[tid] = atomicAdd(&m_arr[b * NK + tid], run);
    atomicMax(&Mbits[b * NK + tid], s_max[tid]);
  }
  __syncthreads();
  for (int j = tid; j < NK * 256; j += 256)
    if (s_hist[j]) atomicAdd(&hist0[b * NK * 256 + j], s_hist[j]);
  #pragma unroll
  for (int j = 0; j < 4; ++j) {
    int c = cls[j];
    clist[(size_t)(b * NK + c) * CCAP + s_bbase[c] + s_segbase[w][j][c] + myoff[j]] = cv[j];
  }
}

// ---------------- A2: radix select with PARALLEL suffix-sum bin selection ----------
// One block per (b,c,t). Replaces all tid==0 serial 256-bin walks with:
//   S[tid] = suffix sum of h over [tid..255]  (shfl scan + 4-wave combine)
//   bin    = popcount(S >= rank) - 1          (S non-increasing -> prefix property)
//   rank  -= S[bin] - h[bin]
__global__ __launch_bounds__(256) void k_thresh(const float* __restrict__ clist,
    const unsigned* __restrict__ hist0, const unsigned* __restrict__ m_arr,
    float* __restrict__ thr) {
  int g = blockIdx.x;
  int bc = g >> 3;
  int t = g & 7;
  int tid = threadIdx.x;
  int w = tid >> 6, lane = tid & 63;
  __shared__ unsigned hist[256];
  __shared__ unsigned s_S[256], s_h[256];
  __shared__ unsigned s_tmp[8];
  unsigned m = m_arr[bc];
  if (m == 0) { if (tid == 0) thr[g] = 0.f; return; }
  unsigned long long ks = ((unsigned long long)m * (unsigned)(t + 1)) / TK;
  unsigned rank = ks ? (unsigned)ks : 1u;
  unsigned prefix = 0;
  const unsigned* lp = (const unsigned*)clist + (size_t)bc * CCAP;
  for (int pass = 0; pass < 4; ++pass) {
    unsigned h;
    if (pass == 0) {
      h = hist0[bc * 256 + tid];             // one coalesced load
    } else {
      int shift = 24 - 8 * pass;             // 16, 8, 0
      hist[tid] = 0u;
      __syncthreads();
      unsigned m4 = m >> 2;
      for (unsigned q = tid; q < m4; q += 256) {
        uint4 u = ((const uint4*)lp)[q];
        if ((u.x >> (shift + 8)) == prefix) atomicAdd(&hist[(u.x >> shift) & 255u], 1u);
        if ((u.y >> (shift + 8)) == prefix) atomicAdd(&hist[(u.y >> shift) & 255u], 1u);
        if ((u.z >> (shift + 8)) == prefix) atomicAdd(&hist[(u.z >> shift) & 255u], 1u);
        if ((u.w >> (shift + 8)) == prefix) atomicAdd(&hist[(u.w >> shift) & 255u], 1u);
      }
      for (unsigned idx = (m4 << 2) + tid; idx < m; idx += 256) {
        unsigned u = lp[idx];
        if ((u >> (shift + 8)) == prefix) atomicAdd(&hist[(u >> shift) & 255u], 1u);
      }
      __syncthreads();
      h = hist[tid];
    }
    // ---- parallel select ----
    unsigned v = h;
    #pragma unroll
    for (int d = 1; d < 64; d <<= 1) {       // intra-wave inclusive suffix scan
      unsigned tt = __shfl_down(v, d, 64);
      if (lane + d < 64) v += tt;
    }
    if (lane == 0) s_tmp[w] = v;             // wave totals
    __syncthreads();
    unsigned add = 0;
    #pragma unroll
    for (int q = 0; q < 4; ++q) if (q > w) add += s_tmp[q];
    unsigned S = v + add;                    // suffix sum over [tid..255]
    s_S[tid] = S; s_h[tid] = h;
    unsigned long long mk = __ballot(S >= rank);
    if (lane == 0) s_tmp[4 + w] = (unsigned)__popcll(mk);
    __syncthreads();
    int bin = (int)(s_tmp[4] + s_tmp[5] + s_tmp[6] + s_tmp[7]) - 1;
    if (bin < 0) bin = 0;
    rank = rank - (s_S[bin] - s_h[bin]);
    prefix = (pass == 0) ? (unsigned)bin : ((prefix << 8) | (unsigned)bin);
    __syncthreads();                         // protect s_tmp/s_S/hist reuse
  }
  if (tid == 0) thr[g] = __uint_as_float(prefix);
}

// ---------------- A3: packed (e | bucket) + deterministic Z partials ----------------
__global__ __launch_bounds__(256) void k_bucket(const float* __restrict__ cert,
    const unsigned char* __restrict__ argm, const unsigned* __restrict__ Mbits,
    const float* __restrict__ thr, unsigned* __restrict__ eb_out,
    float* __restrict__ zpart) {
  __shared__ float zacc[4 * NBUK * 64];
  __shared__ float wpart[4 * NBUK];
  __shared__ float s_thr[NSEL];
  __shared__ float s_M[NB * NK];
  int tid = threadIdx.x;
  int w = tid >> 6, lane = tid & 63;
  float* mycol = zacc + (size_t)w * NBUK * 64 + lane;
  if (tid < NSEL) s_thr[tid] = thr[tid];
  if (tid < NB * NK) s_M[tid] = __uint_as_float(Mbits[tid]);
  #pragma unroll
  for (int k = 0; k < NBUK; ++k) mycol[k * 64] = 0.f;
  __syncthreads();
  int i = blockIdx.x * 256 + tid;
  int n4 = i << 2;
  int b = n4 >> 16;
  int n = n4 & (NPIX - 1);
  float4 cv = *(const float4*)(cert + (size_t)b * NPIX + n);
  unsigned av = *(const unsigned*)(argm + (size_t)b * NPIX + n);
  unsigned evv[4];
  #pragma unroll
  for (int j = 0; j < 4; ++j) {
    int c = (av >> (8 * j)) & 255;
    float ce = (j == 0) ? cv.x : (j == 1) ? cv.y : (j == 2) ? cv.z : cv.w;
    float e = expf(ce - s_M[b * NK + c]);
    const float* tc = &s_thr[(b * NK + c) * TK];
    int tmin = TK - 1;
    #pragma unroll
    for (int tt = TK - 2; tt >= 0; --tt) if (ce >= tc[tt]) tmin = tt;
    evv[j] = (__float_as_uint(e) & 0xFFFFFFC0u) | (unsigned)(c * TK + tmin);
    mycol[(evv[j] & 63u) * 64] += __uint_as_float(evv[j] & 0xFFFF0000u);
  }
  uint4 ev; ev.x = evv[0]; ev.y = evv[1]; ev.z = evv[2]; ev.w = evv[3];
  *(uint4*)(eb_out + (size_t)b * NPIX + n) = ev;
  __syncthreads();
  for (int k = 0; k < NBUK; ++k) {
    float v = mycol[k * 64];
    #pragma unroll
    for (int d = 1; d < 64; d <<= 1) v += __shfl_xor(v, d, 64);
    if (lane == 0) wpart[w * NBUK + k] = v;
  }
  __syncthreads();
  if (tid < NBUK)
    zpart[(size_t)blockIdx.x * NBUK + tid] =
      wpart[tid] + wpart[NBUK + tid] + wpart[2 * NBUK + tid] + wpart[3 * NBUK + tid];
}

// ---------------- Zred ----------------
__global__ __launch_bounds__(192) void k_zred(const float* __restrict__ zpart,
                                              float* __restrict__ zfin) {
  int t = threadIdx.x;
  int b = t / NBUK, k = t % NBUK;
  float s = 0.f;
  for (int i = 0; i < 64; ++i) s += zpart[(size_t)(b * 64 + i) * NBUK + k];
  zfin[b * NBUK + k] = s;
}

// ---------------- B: MFMA GEMM (R11 version, measured 51.3 us ~ roofline) ----------
__global__ __launch_bounds__(512) void k_gemm(const float* __restrict__ x,
    const unsigned* __restrict__ eb, float* __restrict__ psum) {
  __shared__ char smem[49152];
  short* E = (short*)smem;
  int tid = threadIdx.x;
  int w = tid >> 6, lane = tid & 63;
  int bid = blockIdx.x;
  int g = bid & (GB - 1);
  int chh = (bid >> 7) & (CHSP - 1);
  int b = bid >> 8;
  const unsigned* ebp = eb + (size_t)b * NPIX + g * 512;
  const float* xb = x + ((size_t)b * NCH + chh * 128) * NPIX;
  int chl = w * 16 + (lane & 15);
  f32x4 acc[3];
  #pragma unroll
  for (int m = 0; m < 3; ++m) acc[m] = (f32x4){0.f, 0.f, 0.f, 0.f};
  #pragma unroll
  for (int z = 0; z < 6; ++z)
    ((uint4*)E)[z * 512 + tid] = (uint4){0u, 0u, 0u, 0u};
  __syncthreads();
  {
    unsigned u = ebp[tid];
    unsigned bk = u & 63u;
    int ks = tid >> 5, k = tid & 31;
    int el = (int)(bk & 15u) + ((k >> 3) << 4);
    E[((ks * 3 + (int)(bk >> 4)) * 64 + el) * 8 + (k & 7)] = (short)(u >> 16);
  }
  __syncthreads();
  const float* xrow = xb + (size_t)chl * NPIX + g * 512 + ((lane >> 4) << 3);
  float4 xa[4], xc[4];
  #pragma unroll
  for (int p = 0; p < 3; ++p) {
    xa[p] = *(const float4*)(xrow + p * 32);
    xc[p] = *(const float4*)(xrow + p * 32 + 4);
  }
  #pragma unroll
  for (int ks = 0; ks < 16; ++ks) {
    if (ks + 3 < 16) {
      xa[(ks + 3) & 3] = *(const float4*)(xrow + (ks + 3) * 32);
      xc[(ks + 3) & 3] = *(const float4*)(xrow + (ks + 3) * 32 + 4);
    }
    bf16x8 A0 = ((bf16x8*)E)[(ks * 3 + 0) * 64 + lane];
    bf16x8 A1 = ((bf16x8*)E)[(ks * 3 + 1) * 64 + lane];
    bf16x8 A2 = ((bf16x8*)E)[(ks * 3 + 2) * 64 + lane];
    float4 va = xa[ks & 3], vc = xc[ks & 3];
    float xv[8] = {va.x, va.y, va.z, va.w, vc.x, vc.y, vc.z, vc.w};
    bf16x8 Bh, Bl;
    #pragma unroll
    for (int j = 0; j < 8; ++j) {
      unsigned u = __float_as_uint(xv[j]);
      float hf = __uint_as_float(u & 0xFFFF0000u);
      float lo = xv[j] - hf;
      Bh[j] = (short)(u >> 16);
      Bl[j] = (short)(__float_as_uint(lo) >> 16);
    }
    acc[0] = __builtin_amdgcn_mfma_f32_16x16x32_bf16(A0, Bh, acc[0], 0, 0, 0);
    acc[1] = __builtin_amdgcn_mfma_f32_16x16x32_bf16(A1, Bh, acc[1], 0, 0, 0);
    acc[2] = __builtin_amdgcn_mfma_f32_16x16x32_bf16(A2, Bh, acc[2], 0, 0, 0);
    acc[0] = __builtin_amdgcn_mfma_f32_16x16x32_bf16(A0, Bl, acc[0], 0, 0, 0);
    acc[1] = __builtin_amdgcn_mfma_f32_16x16x32_bf16(A1, Bl, acc[1], 0, 0, 0);
    acc[2] = __builtin_amdgcn_mfma_f32_16x16x32_bf16(A2, Bl, acc[2], 0, 0, 0);
  }
  __syncthreads();
  float* Ct = (float*)smem;
  #pragma unroll
  for (int m = 0; m < 3; ++m)
    #pragma unroll
    for (int i = 0; i < 4; ++i)
      Ct[chl * 52 + m * 16 + ((lane >> 4) << 2) + i] = acc[m][i];
  __syncthreads();
  float* dst = psum + ((size_t)g * NB * NCH + (size_t)b * NCH + chh * 128) * NBUK;
  int r = tid >> 2, p = tid & 3;
  #pragma unroll
  for (int j = 0; j < 3; ++j) {
    float4 v = *(const float4*)(Ct + r * 52 + p * 12 + j * 4);
    *(float4*)(dst + r * NBUK + p * 12 + j * 4) = v;
  }
}

// ---------------- F: reduce 128 g-partials, prefix over t, write fs+fg -------
__global__ __launch_bounds__(64) void k_final(const float* __restrict__ psum,
    const float* __restrict__ zfin, const unsigned* __restrict__ m_arr,
    float* __restrict__ out) {
  int bc_ = blockIdx.x;
  int lane = threadIdx.x;
  int b = bc_ >> 8;
  float p48[NBUK];
  #pragma unroll
  for (int k = 0; k < NBUK; ++k) p48[k] = 0.f;
  #pragma unroll
  for (int gg = 0; gg < GB / 64; ++gg) {
    const float* ps = psum + ((size_t)(gg * 64 + lane) * NB * NCH + bc_) * NBUK;
    #pragma unroll
    for (int i = 0; i < 12; ++i) {
      float4 v = ((const float4*)ps)[i];
      p48[4 * i] += v.x; p48[4 * i + 1] += v.y; p48[4 * i + 2] += v.z; p48[4 * i + 3] += v.w;
    }
  }
  #pragma unroll
  for (int d = 1; d < 64; d <<= 1)
    #pragma unroll
    for (int k = 0; k < NBUK; ++k) p48[k] += __shfl_xor(p48[k], d, 64);
  if (lane == 0) {
    float* fs = out + (size_t)bc_ * NBUK;
    float* fg = out + (size_t)NB * NCH * NBUK + (size_t)bc_ * NK;
    float t5[TK];
    #pragma unroll
    for (int c = 0; c < NK; ++c) {
      unsigned m = m_arr[b * NK + c];
      float P = 0.f, Z = 0.f;
      float vals[TK];
      #pragma unroll
      for (int t = 0; t < TK; ++t) {
        P += p48[c * TK + t];
        Z += zfin[b * NBUK + c * TK + t];
        vals[t] = P / Z;
      }
      float tot = vals[TK - 1];
      #pragma unroll
      for (int t = 0; t < TK; ++t) {
        float v = (m == 0u) ? 0.f : ((m < (unsigned)TK) ? tot : vals[t]);
        fs[c * TK + t] = v;
        if (c == NK - 1) t5[t] = v;
      }
    }
    #pragma unroll
    for (int v = 0; v < NK; ++v) fg[v] = t5[2 + v];
  }
}

extern "C" void kernel_launch(void* const* d_in, const int* in_sizes, int n_in,
                              void* d_out, int out_size, void* d_ws, size_t ws_size,
                              hipStream_t stream) {
  const float* x     = (const float*)d_in[0];
  const float* preds = (const float*)d_in[1];
  float* out = (float*)d_out;
  char* ws = (char*)d_ws;
  float*         cert  = (float*)(ws);
  unsigned char* argm  = (unsigned char*)(ws + 0x100000);
  unsigned*      eb    = (unsigned*)(ws + 0x140000);
  float*         clist = (float*)(ws + 0x240000);
  float*         psum  = (float*)(ws + 0x240000);   // union: clist dead after k_thresh
  unsigned*      m_arr = (unsigned*)(ws + 0x1A80000);
  unsigned*      Mbits = (unsigned*)(ws + 0x1A80100);
  float*         thr   = (float*)(ws + 0x1A80200);
  float*         zpart = (float*)(ws + 0x1A81000);
  float*         zfin  = (float*)(ws + 0x1A8E000);
  unsigned*      hist0 = (unsigned*)(ws + 0x1A90000);

  k_init  <<<8, 256, 0, stream>>>(m_arr, Mbits, hist0);
  k_cert  <<<256, 256, 0, stream>>>(preds, cert, argm, m_arr, Mbits, hist0, clist);
  k_thresh<<<NSEL, 256, 0, stream>>>(clist, hist0, m_arr, thr);
  k_bucket<<<256, 256, 0, stream>>>(cert, argm, Mbits, thr, eb, zpart);
  k_zred  <<<1, 192, 0, stream>>>(zpart, zfin);
  k_gemm  <<<NB * CHSP * GB, 512, 0, stream>>>(x, eb, psum);
  k_final <<<NB * NCH, 64, 0, stream>>>(psum, zfin, m_arr, out);
}

// Round 16
// 105.810 us; speedup vs baseline: 32.5282x; 1.1124x over previous
//
#include <hip/hip_runtime.h>
#include <math.h>

#define NPIX 65536
#define NB   4
#define NK   6
#define TK   8
#define NBUK 48
#define NCH  256
#define GB   128
#define GSTEP 2
#define NG2  (GB/GSTEP)   // 64 chunk-groups
#define CHSP 2
#define NSEL (NB*NK*TK)
#define CCAP 65536

typedef __attribute__((ext_vector_type(8))) short bf16x8;
typedef __attribute__((ext_vector_type(4))) float f32x4;

// ---------------- init: zero atomic targets + pass-0 histograms ----------------
__global__ __launch_bounds__(256) void k_init(unsigned* m_arr, unsigned* Mbits,
                                              unsigned* hist0) {
  int i = blockIdx.x * 256 + threadIdx.x;
  if (i < NB * NK) { m_arr[i] = 0u; Mbits[i] = 0u; }
  for (int j = i; j < NB * NK * 256; j += 256 * 8) hist0[j] = 0u;
}

// ---------------- A1: cert/argmax/m/M + pass-0 hist + ballot compaction ----------------
__global__ __launch_bounds__(256) void k_cert(const float* __restrict__ preds,
    float* __restrict__ cert, unsigned char* __restrict__ argm,
    unsigned* __restrict__ m_arr, unsigned* __restrict__ Mbits,
    unsigned* __restrict__ hist0, float* __restrict__ clist) {
  __shared__ unsigned s_max[NK];
  __shared__ unsigned s_hist[NK * 256];
  __shared__ unsigned s_seg[4][4][NK];
  __shared__ unsigned s_segbase[4][4][NK];
  __shared__ unsigned s_bbase[NK];
  int tid = threadIdx.x;
  int w = tid >> 6, lane = tid & 63;
  if (tid < NK) s_max[tid] = 0u;
  for (int j = tid; j < NK * 256; j += 256) s_hist[j] = 0u;
  __syncthreads();
  int i = blockIdx.x * 256 + tid;
  int n4 = i << 2;
  int b = n4 >> 16;
  int n = n4 & (NPIX - 1);
  const float* pb = preds + (size_t)b * NK * NPIX + n;
  float4 pv[NK];
  #pragma unroll
  for (int k = 0; k < NK; ++k) pv[k] = *(const float4*)(pb + (size_t)k * NPIX);
  float cv[4]; int cls[4]; unsigned av = 0;
  #pragma unroll
  for (int j = 0; j < 4; ++j) {
    float m1 = -INFINITY, m2 = -INFINITY; int arg = 0;
    #pragma unroll
    for (int k = 0; k < NK; ++k) {
      float v = (j == 0) ? pv[k].x : (j == 1) ? pv[k].y : (j == 2) ? pv[k].z : pv[k].w;
      if (v > m1) { m2 = m1; m1 = v; arg = k; }
      else if (v > m2) m2 = v;
    }
    cv[j] = m1 - m2;
    cls[j] = arg;
    av |= ((unsigned)arg) << (8 * j);
    unsigned u = __float_as_uint(cv[j]);
    atomicMax(&s_max[arg], u);
    atomicAdd(&s_hist[arg * 256 + (u >> 24)], 1u);
  }
  *(float4*)(cert + (size_t)b * NPIX + n) = make_float4(cv[0], cv[1], cv[2], cv[3]);
  *(unsigned*)(argm + (size_t)b * NPIX + n) = av;
  unsigned long long lmask = ((unsigned long long)1 << lane) - 1ull;
  unsigned myoff[4];
  #pragma unroll
  for (int j = 0; j < 4; ++j) {
    #pragma unroll
    for (int c = 0; c < NK; ++c) {
      unsigned long long mk = __ballot(cls[j] == c);
      if (cls[j] == c) myoff[j] = (unsigned)__popcll(mk & lmask);
      if (lane == 0) s_seg[w][j][c] = (unsigned)__popcll(mk);
    }
  }
  __syncthreads();
  if (tid < NK) {
    unsigned run = 0;
    #pragma unroll
    for (int s = 0; s < 16; ++s) {
      unsigned v = s_seg[s >> 2][s & 3][tid];
      s_segbase[s >> 2][s & 3][tid] = run;
      run += v;
    }
    s_bbase[tid] = atomicAdd(&m_arr[b * NK + tid], run);
    atomicMax(&Mbits[b * NK + tid], s_max[tid]);
  }
  __syncthreads();
  for (int j = tid; j < NK * 256; j += 256)
    if (s_hist[j]) atomicAdd(&hist0[b * NK * 256 + j], s_hist[j]);
  #pragma unroll
  for (int j = 0; j < 4; ++j) {
    int c = cls[j];
    clist[(size_t)(b * NK + c) * CCAP + s_bbase[c] + s_segbase[w][j][c] + myoff[j]] = cv[j];
  }
}

// ---------------- A2: radix select with parallel suffix-sum bin selection ----------
__global__ __launch_bounds__(256) void k_thresh(const float* __restrict__ clist,
    const unsigned* __restrict__ hist0, const unsigned* __restrict__ m_arr,
    float* __restrict__ thr) {
  int g = blockIdx.x;
  int bc = g >> 3;
  int t = g & 7;
  int tid = threadIdx.x;
  int w = tid >> 6, lane = tid & 63;
  __shared__ unsigned hist[256];
  __shared__ unsigned s_S[256], s_h[256];
  __shared__ unsigned s_tmp[8];
  unsigned m = m_arr[bc];
  if (m == 0) { if (tid == 0) thr[g] = 0.f; return; }
  unsigned long long ks = ((unsigned long long)m * (unsigned)(t + 1)) / TK;
  unsigned rank = ks ? (unsigned)ks : 1u;
  unsigned prefix = 0;
  const unsigned* lp = (const unsigned*)clist + (size_t)bc * CCAP;
  for (int pass = 0; pass < 4; ++pass) {
    unsigned h;
    if (pass == 0) {
      h = hist0[bc * 256 + tid];
    } else {
      int shift = 24 - 8 * pass;
      hist[tid] = 0u;
      __syncthreads();
      unsigned m4 = m >> 2;
      for (unsigned q = tid; q < m4; q += 256) {
        uint4 u = ((const uint4*)lp)[q];
        if ((u.x >> (shift + 8)) == prefix) atomicAdd(&hist[(u.x >> shift) & 255u], 1u);
        if ((u.y >> (shift + 8)) == prefix) atomicAdd(&hist[(u.y >> shift) & 255u], 1u);
        if ((u.z >> (shift + 8)) == prefix) atomicAdd(&hist[(u.z >> shift) & 255u], 1u);
        if ((u.w >> (shift + 8)) == prefix) atomicAdd(&hist[(u.w >> shift) & 255u], 1u);
      }
      for (unsigned idx = (m4 << 2) + tid; idx < m; idx += 256) {
        unsigned u = lp[idx];
        if ((u >> (shift + 8)) == prefix) atomicAdd(&hist[(u >> shift) & 255u], 1u);
      }
      __syncthreads();
      h = hist[tid];
    }
    unsigned v = h;
    #pragma unroll
    for (int d = 1; d < 64; d <<= 1) {
      unsigned tt = __shfl_down(v, d, 64);
      if (lane + d < 64) v += tt;
    }
    if (lane == 0) s_tmp[w] = v;
    __syncthreads();
    unsigned add = 0;
    #pragma unroll
    for (int q = 0; q < 4; ++q) if (q > w) add += s_tmp[q];
    unsigned S = v + add;
    s_S[tid] = S; s_h[tid] = h;
    unsigned long long mk = __ballot(S >= rank);
    if (lane == 0) s_tmp[4 + w] = (unsigned)__popcll(mk);
    __syncthreads();
    int bin = (int)(s_tmp[4] + s_tmp[5] + s_tmp[6] + s_tmp[7]) - 1;
    if (bin < 0) bin = 0;
    rank = rank - (s_S[bin] - s_h[bin]);
    prefix = (pass == 0) ? (unsigned)bin : ((prefix << 8) | (unsigned)bin);
    __syncthreads();
  }
  if (tid == 0) thr[g] = __uint_as_float(prefix);
}

// ---------------- A3: packed (e | bucket) + deterministic Z partials ----------------
__global__ __launch_bounds__(256) void k_bucket(const float* __restrict__ cert,
    const unsigned char* __restrict__ argm, const unsigned* __restrict__ Mbits,
    const float* __restrict__ thr, unsigned* __restrict__ eb_out,
    float* __restrict__ zpart) {
  __shared__ float zacc[4 * NBUK * 64];
  __shared__ float wpart[4 * NBUK];
  __shared__ float s_thr[NSEL];
  __shared__ float s_M[NB * NK];
  int tid = threadIdx.x;
  int w = tid >> 6, lane = tid & 63;
  float* mycol = zacc + (size_t)w * NBUK * 64 + lane;
  if (tid < NSEL) s_thr[tid] = thr[tid];
  if (tid < NB * NK) s_M[tid] = __uint_as_float(Mbits[tid]);
  #pragma unroll
  for (int k = 0; k < NBUK; ++k) mycol[k * 64] = 0.f;
  __syncthreads();
  int i = blockIdx.x * 256 + tid;
  int n4 = i << 2;
  int b = n4 >> 16;
  int n = n4 & (NPIX - 1);
  float4 cv = *(const float4*)(cert + (size_t)b * NPIX + n);
  unsigned av = *(const unsigned*)(argm + (size_t)b * NPIX + n);
  unsigned evv[4];
  #pragma unroll
  for (int j = 0; j < 4; ++j) {
    int c = (av >> (8 * j)) & 255;
    float ce = (j == 0) ? cv.x : (j == 1) ? cv.y : (j == 2) ? cv.z : cv.w;
    float e = expf(ce - s_M[b * NK + c]);
    const float* tc = &s_thr[(b * NK + c) * TK];
    int tmin = TK - 1;
    #pragma unroll
    for (int tt = TK - 2; tt >= 0; --tt) if (ce >= tc[tt]) tmin = tt;
    evv[j] = (__float_as_uint(e) & 0xFFFFFFC0u) | (unsigned)(c * TK + tmin);
    mycol[(evv[j] & 63u) * 64] += __uint_as_float(evv[j] & 0xFFFF0000u);
  }
  uint4 ev; ev.x = evv[0]; ev.y = evv[1]; ev.z = evv[2]; ev.w = evv[3];
  *(uint4*)(eb_out + (size_t)b * NPIX + n) = ev;
  __syncthreads();
  for (int k = 0; k < NBUK; ++k) {
    float v = mycol[k * 64];
    #pragma unroll
    for (int d = 1; d < 64; d <<= 1) v += __shfl_xor(v, d, 64);
    if (lane == 0) wpart[w * NBUK + k] = v;
  }
  __syncthreads();
  if (tid < NBUK)
    zpart[(size_t)blockIdx.x * NBUK + tid] =
      wpart[tid] + wpart[NBUK + tid] + wpart[2 * NBUK + tid] + wpart[3 * NBUK + tid];
}

// ---------------- B: MFMA GEMM, GSTEP=2 chunks per block ----------
// grid = NB*CHSP*NG2 = 512 blocks, 512 thr.
__global__ __launch_bounds__(512) void k_gemm(const float* __restrict__ x,
    const unsigned* __restrict__ eb, float* __restrict__ psum) {
  __shared__ char smem[49152];
  short* E = (short*)smem;
  int tid = threadIdx.x;
  int w = tid >> 6, lane = tid & 63;
  int bid = blockIdx.x;
  int g2 = bid & (NG2 - 1);
  int chh = (bid >> 6) & (CHSP - 1);
  int b = bid >> 7;
  const float* xb = x + ((size_t)b * NCH + chh * 128) * NPIX;
  int chl = w * 16 + (lane & 15);
  f32x4 acc[3];
  #pragma unroll
  for (int m = 0; m < 3; ++m) acc[m] = (f32x4){0.f, 0.f, 0.f, 0.f};
  for (int cg = 0; cg < GSTEP; ++cg) {
    int g = g2 * GSTEP + cg;
    const unsigned* ebp = eb + (size_t)b * NPIX + g * 512;
    __syncthreads();                        // prior E readers done
    #pragma unroll
    for (int z = 0; z < 6; ++z)
      ((uint4*)E)[z * 512 + tid] = (uint4){0u, 0u, 0u, 0u};
    __syncthreads();
    {
      unsigned u = ebp[tid];
      unsigned bk = u & 63u;
      int ks = tid >> 5, k = tid & 31;
      int el = (int)(bk & 15u) + ((k >> 3) << 4);
      E[((ks * 3 + (int)(bk >> 4)) * 64 + el) * 8 + (k & 7)] = (short)(u >> 16);
    }
    __syncthreads();
    const float* xrow = xb + (size_t)chl * NPIX + g * 512 + ((lane >> 4) << 3);
    float4 xa[4], xc[4];
    #pragma unroll
    for (int p = 0; p < 3; ++p) {
      xa[p] = *(const float4*)(xrow + p * 32);
      xc[p] = *(const float4*)(xrow + p * 32 + 4);
    }
    #pragma unroll
    for (int ks = 0; ks < 16; ++ks) {
      if (ks + 3 < 16) {
        xa[(ks + 3) & 3] = *(const float4*)(xrow + (ks + 3) * 32);
        xc[(ks + 3) & 3] = *(const float4*)(xrow + (ks + 3) * 32 + 4);
      }
      bf16x8 A0 = ((bf16x8*)E)[(ks * 3 + 0) * 64 + lane];
      bf16x8 A1 = ((bf16x8*)E)[(ks * 3 + 1) * 64 + lane];
      bf16x8 A2 = ((bf16x8*)E)[(ks * 3 + 2) * 64 + lane];
      float4 va = xa[ks & 3], vc = xc[ks & 3];
      float xv[8] = {va.x, va.y, va.z, va.w, vc.x, vc.y, vc.z, vc.w};
      bf16x8 Bh, Bl;
      #pragma unroll
      for (int j = 0; j < 8; ++j) {
        unsigned u = __float_as_uint(xv[j]);
        float hf = __uint_as_float(u & 0xFFFF0000u);   // truncated-bf16 hi
        float lo = xv[j] - hf;                          // exact residual
        Bh[j] = (short)(u >> 16);
        Bl[j] = (short)(__float_as_uint(lo) >> 16);
      }
      acc[0] = __builtin_amdgcn_mfma_f32_16x16x32_bf16(A0, Bh, acc[0], 0, 0, 0);
      acc[1] = __builtin_amdgcn_mfma_f32_16x16x32_bf16(A1, Bh, acc[1], 0, 0, 0);
      acc[2] = __builtin_amdgcn_mfma_f32_16x16x32_bf16(A2, Bh, acc[2], 0, 0, 0);
      acc[0] = __builtin_amdgcn_mfma_f32_16x16x32_bf16(A0, Bl, acc[0], 0, 0, 0);
      acc[1] = __builtin_amdgcn_mfma_f32_16x16x32_bf16(A1, Bl, acc[1], 0, 0, 0);
      acc[2] = __builtin_amdgcn_mfma_f32_16x16x32_bf16(A2, Bl, acc[2], 0, 0, 0);
    }
  }
  // epilogue: C layout col=lane&15 (ch), row=(lane>>4)*4+i (bucket) [m89-verified]
  __syncthreads();
  float* Ct = (float*)smem;                 // [128][52] padded
  #pragma unroll
  for (int m = 0; m < 3; ++m)
    #pragma unroll
    for (int i = 0; i < 4; ++i)
      Ct[chl * 52 + m * 16 + ((lane >> 4) << 2) + i] = acc[m][i];
  __syncthreads();
  float* dst = psum + ((size_t)g2 * NB * NCH + (size_t)b * NCH + chh * 128) * NBUK;
  int r = tid >> 2, p = tid & 3;
  #pragma unroll
  for (int j = 0; j < 3; ++j) {
    float4 v = *(const float4*)(Ct + r * 52 + p * 12 + j * 4);
    *(float4*)(dst + r * NBUK + p * 12 + j * 4) = v;
  }
}

// ---------------- F: reduce 64 g2-partials (P) + 64 seg-partials (Z), write fs+fg ----
__global__ __launch_bounds__(64) void k_final(const float* __restrict__ psum,
    const float* __restrict__ zpart, const unsigned* __restrict__ m_arr,
    float* __restrict__ out) {
  int bc_ = blockIdx.x;                     // (b*NCH + ch), 1024 blocks
  int lane = threadIdx.x;                   // = g2 for P, = seg for Z
  int b = bc_ >> 8;
  float p48[NBUK], z48[NBUK];
  const float* ps = psum + ((size_t)lane * NB * NCH + bc_) * NBUK;
  const float* zp = zpart + (size_t)(b * 64 + lane) * NBUK;
  #pragma unroll
  for (int i = 0; i < 12; ++i) {
    float4 v = ((const float4*)ps)[i];
    p48[4*i] = v.x; p48[4*i+1] = v.y; p48[4*i+2] = v.z; p48[4*i+3] = v.w;
    float4 zv = ((const float4*)zp)[i];
    z48[4*i] = zv.x; z48[4*i+1] = zv.y; z48[4*i+2] = zv.z; z48[4*i+3] = zv.w;
  }
  #pragma unroll
  for (int d = 1; d < 64; d <<= 1)
    #pragma unroll
    for (int k = 0; k < NBUK; ++k) {
      p48[k] += __shfl_xor(p48[k], d, 64);
      z48[k] += __shfl_xor(z48[k], d, 64);
    }
  if (lane == 0) {
    float* fs = out + (size_t)bc_ * NBUK;
    float* fg = out + (size_t)NB * NCH * NBUK + (size_t)bc_ * NK;
    float t5[TK];
    #pragma unroll
    for (int c = 0; c < NK; ++c) {
      unsigned m = m_arr[b * NK + c];
      float P = 0.f, Z = 0.f;
      float vals[TK];
      #pragma unroll
      for (int t = 0; t < TK; ++t) {
        P += p48[c * TK + t];
        Z += z48[c * TK + t];
        vals[t] = P / Z;
      }
      float tot = vals[TK - 1];
      #pragma unroll
      for (int t = 0; t < TK; ++t) {
        float v = (m == 0u) ? 0.f : ((m < (unsigned)TK) ? tot : vals[t]);
        fs[c * TK + t] = v;
        if (c == NK - 1) t5[t] = v;
      }
    }
    #pragma unroll
    for (int v = 0; v < NK; ++v) fg[v] = t5[2 + v];
  }
}

extern "C" void kernel_launch(void* const* d_in, const int* in_sizes, int n_in,
                              void* d_out, int out_size, void* d_ws, size_t ws_size,
                              hipStream_t stream) {
  const float* x     = (const float*)d_in[0];
  const float* preds = (const float*)d_in[1];
  float* out = (float*)d_out;
  char* ws = (char*)d_ws;
  float*         cert  = (float*)(ws);
  unsigned char* argm  = (unsigned char*)(ws + 0x100000);
  unsigned*      eb    = (unsigned*)(ws + 0x140000);
  float*         clist = (float*)(ws + 0x240000);
  float*         psum  = (float*)(ws + 0x240000);   // union: clist dead after k_thresh
  unsigned*      m_arr = (unsigned*)(ws + 0x1A80000);
  unsigned*      Mbits = (unsigned*)(ws + 0x1A80100);
  float*         thr   = (float*)(ws + 0x1A80200);
  float*         zpart = (float*)(ws + 0x1A81000);  // 48 KiB
  unsigned*      hist0 = (unsigned*)(ws + 0x1A90000);

  k_init  <<<8, 256, 0, stream>>>(m_arr, Mbits, hist0);
  k_cert  <<<256, 256, 0, stream>>>(preds, cert, argm, m_arr, Mbits, hist0, clist);
  k_thresh<<<NSEL, 256, 0, stream>>>(clist, hist0, m_arr, thr);
  k_bucket<<<256, 256, 0, stream>>>(cert, argm, Mbits, thr, eb, zpart);
  k_gemm  <<<NB * CHSP * NG2, 512, 0, stream>>>(x, eb, psum);
  k_final <<<NB * NCH, 64, 0, stream>>>(psum, zpart, m_arr, out);
}

// Round 17
// 92.667 us; speedup vs baseline: 37.1415x; 1.1418x over previous
//
#include <hip/hip_runtime.h>
#include <math.h>

#define NPIX 65536
#define NB   4
#define NK   6
#define TK   8
#define NBUK 48
#define NCH  256
#define GB   128
#define GSTEP 2
#define NG2  (GB/GSTEP)   // 64 chunk-groups
#define CHSP 2
#define NSEL (NB*NK*TK)
#define CCAP 65536

typedef __attribute__((ext_vector_type(8))) short bf16x8;
typedef __attribute__((ext_vector_type(4))) float f32x4;

// ---------------- init: zero atomic targets + pass-0 histograms ----------------
__global__ __launch_bounds__(256) void k_init(unsigned* m_arr, unsigned* Mbits,
                                              unsigned* hist0) {
  int i = blockIdx.x * 256 + threadIdx.x;
  if (i < NB * NK) { m_arr[i] = 0u; Mbits[i] = 0u; }
  for (int j = i; j < NB * NK * 256; j += 256 * 8) hist0[j] = 0u;
}

// ---------------- A1: cert/argmax/m/M + pass-0 hist + ballot compaction ----------------
__global__ __launch_bounds__(256) void k_cert(const float* __restrict__ preds,
    float* __restrict__ cert, unsigned char* __restrict__ argm,
    unsigned* __restrict__ m_arr, unsigned* __restrict__ Mbits,
    unsigned* __restrict__ hist0, float* __restrict__ clist) {
  __shared__ unsigned s_max[NK];
  __shared__ unsigned s_hist[NK * 256];
  __shared__ unsigned s_seg[4][4][NK];
  __shared__ unsigned s_segbase[4][4][NK];
  __shared__ unsigned s_bbase[NK];
  int tid = threadIdx.x;
  int w = tid >> 6, lane = tid & 63;
  if (tid < NK) s_max[tid] = 0u;
  for (int j = tid; j < NK * 256; j += 256) s_hist[j] = 0u;
  __syncthreads();
  int i = blockIdx.x * 256 + tid;
  int n4 = i << 2;
  int b = n4 >> 16;
  int n = n4 & (NPIX - 1);
  const float* pb = preds + (size_t)b * NK * NPIX + n;
  float4 pv[NK];
  #pragma unroll
  for (int k = 0; k < NK; ++k) pv[k] = *(const float4*)(pb + (size_t)k * NPIX);
  float cv[4]; int cls[4]; unsigned av = 0;
  #pragma unroll
  for (int j = 0; j < 4; ++j) {
    float m1 = -INFINITY, m2 = -INFINITY; int arg = 0;
    #pragma unroll
    for (int k = 0; k < NK; ++k) {
      float v = (j == 0) ? pv[k].x : (j == 1) ? pv[k].y : (j == 2) ? pv[k].z : pv[k].w;
      if (v > m1) { m2 = m1; m1 = v; arg = k; }
      else if (v > m2) m2 = v;
    }
    cv[j] = m1 - m2;
    cls[j] = arg;
    av |= ((unsigned)arg) << (8 * j);
    unsigned u = __float_as_uint(cv[j]);
    atomicMax(&s_max[arg], u);
    atomicAdd(&s_hist[arg * 256 + (u >> 24)], 1u);
  }
  *(float4*)(cert + (size_t)b * NPIX + n) = make_float4(cv[0], cv[1], cv[2], cv[3]);
  *(unsigned*)(argm + (size_t)b * NPIX + n) = av;
  unsigned long long lmask = ((unsigned long long)1 << lane) - 1ull;
  unsigned myoff[4];
  #pragma unroll
  for (int j = 0; j < 4; ++j) {
    #pragma unroll
    for (int c = 0; c < NK; ++c) {
      unsigned long long mk = __ballot(cls[j] == c);
      if (cls[j] == c) myoff[j] = (unsigned)__popcll(mk & lmask);
      if (lane == 0) s_seg[w][j][c] = (unsigned)__popcll(mk);
    }
  }
  __syncthreads();
  if (tid < NK) {
    unsigned run = 0;
    #pragma unroll
    for (int s = 0; s < 16; ++s) {
      unsigned v = s_seg[s >> 2][s & 3][tid];
      s_segbase[s >> 2][s & 3][tid] = run;
      run += v;
    }
    s_bbase[tid] = atomicAdd(&m_arr[b * NK + tid], run);
    atomicMax(&Mbits[b * NK + tid], s_max[tid]);
  }
  __syncthreads();
  for (int j = tid; j < NK * 256; j += 256)
    if (s_hist[j]) atomicAdd(&hist0[b * NK * 256 + j], s_hist[j]);
  #pragma unroll
  for (int j = 0; j < 4; ++j) {
    int c = cls[j];
    clist[(size_t)(b * NK + c) * CCAP + s_bbase[c] + s_segbase[w][j][c] + myoff[j]] = cv[j];
  }
}

// ---------------- A2: radix select with parallel suffix-sum bin selection ----------
__global__ __launch_bounds__(256) void k_thresh(const float* __restrict__ clist,
    const unsigned* __restrict__ hist0, const unsigned* __restrict__ m_arr,
    float* __restrict__ thr) {
  int g = blockIdx.x;
  int bc = g >> 3;
  int t = g & 7;
  int tid = threadIdx.x;
  int w = tid >> 6, lane = tid & 63;
  __shared__ unsigned hist[256];
  __shared__ unsigned s_S[256], s_h[256];
  __shared__ unsigned s_tmp[8];
  unsigned m = m_arr[bc];
  if (m == 0) { if (tid == 0) thr[g] = 0.f; return; }
  unsigned long long ks = ((unsigned long long)m * (unsigned)(t + 1)) / TK;
  unsigned rank = ks ? (unsigned)ks : 1u;
  unsigned prefix = 0;
  const unsigned* lp = (const unsigned*)clist + (size_t)bc * CCAP;
  for (int pass = 0; pass < 4; ++pass) {
    unsigned h;
    if (pass == 0) {
      h = hist0[bc * 256 + tid];
    } else {
      int shift = 24 - 8 * pass;
      hist[tid] = 0u;
      __syncthreads();
      unsigned m4 = m >> 2;
      for (unsigned q = tid; q < m4; q += 256) {
        uint4 u = ((const uint4*)lp)[q];
        if ((u.x >> (shift + 8)) == prefix) atomicAdd(&hist[(u.x >> shift) & 255u], 1u);
        if ((u.y >> (shift + 8)) == prefix) atomicAdd(&hist[(u.y >> shift) & 255u], 1u);
        if ((u.z >> (shift + 8)) == prefix) atomicAdd(&hist[(u.z >> shift) & 255u], 1u);
        if ((u.w >> (shift + 8)) == prefix) atomicAdd(&hist[(u.w >> shift) & 255u], 1u);
      }
      for (unsigned idx = (m4 << 2) + tid; idx < m; idx += 256) {
        unsigned u = lp[idx];
        if ((u >> (shift + 8)) == prefix) atomicAdd(&hist[(u >> shift) & 255u], 1u);
      }
      __syncthreads();
      h = hist[tid];
    }
    unsigned v = h;
    #pragma unroll
    for (int d = 1; d < 64; d <<= 1) {
      unsigned tt = __shfl_down(v, d, 64);
      if (lane + d < 64) v += tt;
    }
    if (lane == 0) s_tmp[w] = v;
    __syncthreads();
    unsigned add = 0;
    #pragma unroll
    for (int q = 0; q < 4; ++q) if (q > w) add += s_tmp[q];
    unsigned S = v + add;
    s_S[tid] = S; s_h[tid] = h;
    unsigned long long mk = __ballot(S >= rank);
    if (lane == 0) s_tmp[4 + w] = (unsigned)__popcll(mk);
    __syncthreads();
    int bin = (int)(s_tmp[4] + s_tmp[5] + s_tmp[6] + s_tmp[7]) - 1;
    if (bin < 0) bin = 0;
    rank = rank - (s_S[bin] - s_h[bin]);
    prefix = (pass == 0) ? (unsigned)bin : ((prefix << 8) | (unsigned)bin);
    __syncthreads();
  }
  if (tid == 0) thr[g] = __uint_as_float(prefix);
}

// ---------------- B: MFMA GEMM, inline e/bucket (R13-verified), fused Z via E*ones ----
// grid = NB*CHSP*NG2 = 512 blocks, 512 thr; GSTEP=2 chunks per block.
__global__ __launch_bounds__(512) void k_gemm(const float* __restrict__ x,
    const float* __restrict__ cert, const unsigned char* __restrict__ argm,
    const float* __restrict__ thr, const unsigned* __restrict__ Mbits,
    float* __restrict__ psum, float* __restrict__ zpart) {
  __shared__ char smem[49152];              // E (48KB bf16), reused as Ct f32[128][52]
  __shared__ float s_thr[NBUK];
  __shared__ float s_M[NK];
  short* E = (short*)smem;
  int tid = threadIdx.x;
  int w = tid >> 6, lane = tid & 63;
  int bid = blockIdx.x;
  int g2 = bid & (NG2 - 1);
  int chh = (bid >> 6) & (CHSP - 1);
  int b = bid >> 7;
  if (tid < NBUK) s_thr[tid] = thr[b * NBUK + tid];
  if (tid < NK) s_M[tid] = __uint_as_float(Mbits[b * NK + tid]);
  const float* certb = cert + (size_t)b * NPIX;
  const unsigned char* argmb = argm + (size_t)b * NPIX;
  const float* xb = x + ((size_t)b * NCH + chh * 128) * NPIX;
  int chl = w * 16 + (lane & 15);
  f32x4 acc[3], accz[3];
  #pragma unroll
  for (int m = 0; m < 3; ++m) { acc[m] = (f32x4){0.f,0.f,0.f,0.f}; accz[m] = (f32x4){0.f,0.f,0.f,0.f}; }
  bf16x8 Bones;
  #pragma unroll
  for (int j = 0; j < 8; ++j) Bones[j] = (short)0x3F80;   // bf16 1.0
  for (int cg = 0; cg < GSTEP; ++cg) {
    int g = g2 * GSTEP + cg;
    int base = g * 512;
    __syncthreads();                        // prior E readers done (also covers s_thr/s_M init)
    #pragma unroll
    for (int z = 0; z < 6; ++z)
      ((uint4*)E)[z * 512 + tid] = (uint4){0u, 0u, 0u, 0u};
    __syncthreads();
    {                                        // inline e/bucket + scatter (collision-free)
      float ce = certb[base + tid];
      int c = (int)argmb[base + tid];
      float e = expf(ce - s_M[c]);
      const float* tc = &s_thr[c * TK];
      int tmin = TK - 1;
      #pragma unroll
      for (int tt = TK - 2; tt >= 0; --tt) if (ce >= tc[tt]) tmin = tt;
      unsigned bk = (unsigned)(c * TK + tmin);
      int ksx = tid >> 5, k = tid & 31;
      int el = (int)(bk & 15u) + ((k >> 3) << 4);
      E[((ksx * 3 + (int)(bk >> 4)) * 64 + el) * 8 + (k & 7)] = (short)(__float_as_uint(e) >> 16);
    }
    __syncthreads();
    const float* xrow = xb + (size_t)chl * NPIX + base + ((lane >> 4) << 3);
    float4 xa[4], xc[4];
    #pragma unroll
    for (int p = 0; p < 3; ++p) {
      xa[p] = *(const float4*)(xrow + p * 32);
      xc[p] = *(const float4*)(xrow + p * 32 + 4);
    }
    #pragma unroll
    for (int ks = 0; ks < 16; ++ks) {
      if (ks + 3 < 16) {
        xa[(ks + 3) & 3] = *(const float4*)(xrow + (ks + 3) * 32);
        xc[(ks + 3) & 3] = *(const float4*)(xrow + (ks + 3) * 32 + 4);
      }
      bf16x8 A0 = ((bf16x8*)E)[(ks * 3 + 0) * 64 + lane];
      bf16x8 A1 = ((bf16x8*)E)[(ks * 3 + 1) * 64 + lane];
      bf16x8 A2 = ((bf16x8*)E)[(ks * 3 + 2) * 64 + lane];
      float4 va = xa[ks & 3], vc = xc[ks & 3];
      float xv[8] = {va.x, va.y, va.z, va.w, vc.x, vc.y, vc.z, vc.w};
      bf16x8 Bh, Bl;
      #pragma unroll
      for (int j = 0; j < 8; ++j) {
        unsigned u = __float_as_uint(xv[j]);
        float hf = __uint_as_float(u & 0xFFFF0000u);   // truncated-bf16 hi
        float lo = xv[j] - hf;                          // exact residual
        Bh[j] = (short)(u >> 16);
        Bl[j] = (short)(__float_as_uint(lo) >> 16);
      }
      acc[0] = __builtin_amdgcn_mfma_f32_16x16x32_bf16(A0, Bh, acc[0], 0, 0, 0);
      acc[1] = __builtin_amdgcn_mfma_f32_16x16x32_bf16(A1, Bh, acc[1], 0, 0, 0);
      acc[2] = __builtin_amdgcn_mfma_f32_16x16x32_bf16(A2, Bh, acc[2], 0, 0, 0);
      acc[0] = __builtin_amdgcn_mfma_f32_16x16x32_bf16(A0, Bl, acc[0], 0, 0, 0);
      acc[1] = __builtin_amdgcn_mfma_f32_16x16x32_bf16(A1, Bl, acc[1], 0, 0, 0);
      acc[2] = __builtin_amdgcn_mfma_f32_16x16x32_bf16(A2, Bl, acc[2], 0, 0, 0);
      if (chh == 0) {                        // Z = E * ones (same truncated e as P)
        accz[0] = __builtin_amdgcn_mfma_f32_16x16x32_bf16(A0, Bones, accz[0], 0, 0, 0);
        accz[1] = __builtin_amdgcn_mfma_f32_16x16x32_bf16(A1, Bones, accz[1], 0, 0, 0);
        accz[2] = __builtin_amdgcn_mfma_f32_16x16x32_bf16(A2, Bones, accz[2], 0, 0, 0);
      }
    }
  }
  // epilogue: C layout col=lane&15 (ch), row=(lane>>4)*4+i (bucket) [m89-verified]
  __syncthreads();
  float* Ct = (float*)smem;                 // [128][52] padded
  #pragma unroll
  for (int m = 0; m < 3; ++m)
    #pragma unroll
    for (int i = 0; i < 4; ++i)
      Ct[chl * 52 + m * 16 + ((lane >> 4) << 2) + i] = acc[m][i];
  if (chh == 0 && (lane & 15) == 0 && w == 0) {   // col 0 of Z fragment (all cols equal)
    #pragma unroll
    for (int m = 0; m < 3; ++m)
      #pragma unroll
      for (int i = 0; i < 4; ++i)
        zpart[((size_t)b * NG2 + g2) * NBUK + m * 16 + ((lane >> 4) << 2) + i] = accz[m][i];
  }
  __syncthreads();
  float* dst = psum + ((size_t)g2 * NB * NCH + (size_t)b * NCH + chh * 128) * NBUK;
  int r = tid >> 2, p = tid & 3;
  #pragma unroll
  for (int j = 0; j < 3; ++j) {
    float4 v = *(const float4*)(Ct + r * 52 + p * 12 + j * 4);
    *(float4*)(dst + r * NBUK + p * 12 + j * 4) = v;
  }
}

// ---------------- F: reduce 64 g2-partials (P) + 64 Z-partials, write fs+fg ----
__global__ __launch_bounds__(64) void k_final(const float* __restrict__ psum,
    const float* __restrict__ zpart, const unsigned* __restrict__ m_arr,
    float* __restrict__ out) {
  int bc_ = blockIdx.x;                     // (b*NCH + ch), 1024 blocks
  int lane = threadIdx.x;                   // = g2
  int b = bc_ >> 8;
  float p48[NBUK], z48[NBUK];
  const float* ps = psum + ((size_t)lane * NB * NCH + bc_) * NBUK;
  const float* zp = zpart + (size_t)(b * NG2 + lane) * NBUK;
  #pragma unroll
  for (int i = 0; i < 12; ++i) {
    float4 v = ((const float4*)ps)[i];
    p48[4*i] = v.x; p48[4*i+1] = v.y; p48[4*i+2] = v.z; p48[4*i+3] = v.w;
    float4 zv = ((const float4*)zp)[i];
    z48[4*i] = zv.x; z48[4*i+1] = zv.y; z48[4*i+2] = zv.z; z48[4*i+3] = zv.w;
  }
  #pragma unroll
  for (int d = 1; d < 64; d <<= 1)
    #pragma unroll
    for (int k = 0; k < NBUK; ++k) {
      p48[k] += __shfl_xor(p48[k], d, 64);
      z48[k] += __shfl_xor(z48[k], d, 64);
    }
  if (lane == 0) {
    float* fs = out + (size_t)bc_ * NBUK;
    float* fg = out + (size_t)NB * NCH * NBUK + (size_t)bc_ * NK;
    float t5[TK];
    #pragma unroll
    for (int c = 0; c < NK; ++c) {
      unsigned m = m_arr[b * NK + c];
      float P = 0.f, Z = 0.f;
      float vals[TK];
      #pragma unroll
      for (int t = 0; t < TK; ++t) {
        P += p48[c * TK + t];
        Z += z48[c * TK + t];
        vals[t] = P / Z;
      }
      float tot = vals[TK - 1];
      #pragma unroll
      for (int t = 0; t < TK; ++t) {
        float v = (m == 0u) ? 0.f : ((m < (unsigned)TK) ? tot : vals[t]);
        fs[c * TK + t] = v;
        if (c == NK - 1) t5[t] = v;
      }
    }
    #pragma unroll
    for (int v = 0; v < NK; ++v) fg[v] = t5[2 + v];
  }
}

extern "C" void kernel_launch(void* const* d_in, const int* in_sizes, int n_in,
                              void* d_out, int out_size, void* d_ws, size_t ws_size,
                              hipStream_t stream) {
  const float* x     = (const float*)d_in[0];
  const float* preds = (const float*)d_in[1];
  float* out = (float*)d_out;
  char* ws = (char*)d_ws;
  float*         cert  = (float*)(ws);
  unsigned char* argm  = (unsigned char*)(ws + 0x100000);
  float*         clist = (float*)(ws + 0x240000);
  float*         psum  = (float*)(ws + 0x240000);   // union: clist dead after k_thresh
  unsigned*      m_arr = (unsigned*)(ws + 0x1A80000);
  unsigned*      Mbits = (unsigned*)(ws + 0x1A80100);
  float*         thr   = (float*)(ws + 0x1A80200);
  float*         zpart = (float*)(ws + 0x1A81000);  // 48 KiB
  unsigned*      hist0 = (unsigned*)(ws + 0x1A90000);

  k_init  <<<8, 256, 0, stream>>>(m_arr, Mbits, hist0);
  k_cert  <<<256, 256, 0, stream>>>(preds, cert, argm, m_arr, Mbits, hist0, clist);
  k_thresh<<<NSEL, 256, 0, stream>>>(clist, hist0, m_arr, thr);
  k_gemm  <<<NB * CHSP * NG2, 512, 0, stream>>>(x, cert, argm, thr, Mbits, psum, zpart);
  k_final <<<NB * NCH, 64, 0, stream>>>(psum, zpart, m_arr, out);
}